// Round 1
// baseline (53.743 us; speedup 1.0000x reference)
//
#include <hip/hip_runtime.h>

// Problem constants (from setup_inputs): B=32768, D=1024, K=8, NS=10
#define D_LEN 1024
#define K_LEN 8
#define PAD   7            // K-1
#define LC    516          // ((D + 2*PAD) - K)/2 + 1 = (1038-8)/2+1
#define NS    10

// One block (256 threads) per row.
// Phase 1: row -> LDS (float4 coalesced). Filters -> registers (scalar loads).
// Phase 2: lo[c], hi[c] = conv(reflect-pad(x), dec[::-1], stride 2); sparse add.
// Phase 3: rec[t] = corr(reflect-pad(upsample2(lo)), rec_lo) + same for hi;
//          out = x + rec.  Reflection preserves parity -> only 4 taps/filter.
__global__ __launch_bounds__(256) void wavecore_kernel(
    const float* __restrict__ x,
    const float* __restrict__ dec_lo, const float* __restrict__ dec_hi,
    const float* __restrict__ rec_lo, const float* __restrict__ rec_hi,
    const float* __restrict__ sp_c,   const int* __restrict__ sp_i,
    float* __restrict__ out)
{
    __shared__ float sx[D_LEN];
    __shared__ float slo[LC];
    __shared__ float shi[LC];

    const int tid = threadIdx.x;
    const int b   = blockIdx.x;
    const float* xrow = x + (size_t)b * D_LEN;

    // ---- Phase 1: load row (coalesced float4), keep our 4 elems in regs ----
    float4 xv = ((const float4*)xrow)[tid];
    ((float4*)sx)[tid] = xv;

    // Filters: uniform addresses -> compiler emits scalar (SGPR) loads.
    float f_dlo[K_LEN], f_dhi[K_LEN], f_rlo[K_LEN], f_rhi[K_LEN];
#pragma unroll
    for (int k = 0; k < K_LEN; ++k) {
        f_dlo[k] = dec_lo[k];
        f_dhi[k] = dec_hi[k];
        f_rlo[k] = rec_lo[k];
        f_rhi[k] = rec_hi[k];
    }
    __syncthreads();

    // ---- Phase 2: decomposition (stride-2 conv with reflect padding) ----
    // lo[c] = sum_k xp[2c+k] * dec_lo[7-k],  xp[i] = sx[reflect(i-7)]
#pragma unroll
    for (int it = 0; it < 3; ++it) {
        int c = tid + it * 256;
        if (c < LC) {
            float accL = 0.f, accH = 0.f;
#pragma unroll
            for (int k = 0; k < K_LEN; ++k) {
                int m = 2 * c + k - PAD;
                m = (m < 0) ? -m : ((m > D_LEN - 1) ? 2 * (D_LEN - 1) - m : m);
                float v = sx[m];
                accL += v * f_dlo[PAD - k];
                accH += v * f_dhi[PAD - k];
            }
            slo[c] = accL;
            shi[c] = accH;
        }
    }
    __syncthreads();

    // ---- Sparse add: indices are a permutation subset of [0,1024) ----
    if (tid < NS) {
        int s = sp_i[tid];
        float vadd = sp_c[tid];
        if (s < LC) slo[s] += vadd;
        else        shi[s - LC] += vadd;
    }
    __syncthreads();

    // ---- Phase 3: reconstruction + residual ----
    // rec[t] = sum_k up_p[t+k]*rec_lo[k] + ..., up_p[j] = up[reflect2(j-7)],
    // up[m] = (m even) ? lo[m/2] : 0. Reflection preserves parity, so the
    // contributing taps have k parity == (t+1)&1, known at compile time since
    // t = 4*tid + j  =>  t&1 == j&1.
    const int t0 = tid * 4;
    float res[4];
#pragma unroll
    for (int j = 0; j < 4; ++j) {
        const int t  = t0 + j;
        const int k0 = ((j & 1) ^ 1);   // even t: k in {1,3,5,7}; odd t: {0,2,4,6}
        float acc = 0.f;
#pragma unroll
        for (int i = 0; i < 4; ++i) {
            const int k = k0 + 2 * i;
            int m = t + k - PAD;                 // in [-7, 1023]; upper edge never hit
            m = (m < 0) ? -m : m;
            const int c = m >> 1;
            acc += slo[c] * f_rlo[k] + shi[c] * f_rhi[k];
        }
        res[j] = acc;
    }

    float4 r;
    r.x = res[0] + xv.x;
    r.y = res[1] + xv.y;
    r.z = res[2] + xv.z;
    r.w = res[3] + xv.w;
    ((float4*)(out + (size_t)b * D_LEN))[tid] = r;
}

extern "C" void kernel_launch(void* const* d_in, const int* in_sizes, int n_in,
                              void* d_out, int out_size, void* d_ws, size_t ws_size,
                              hipStream_t stream) {
    const float* x      = (const float*)d_in[0];
    const float* dec_lo = (const float*)d_in[1];
    const float* dec_hi = (const float*)d_in[2];
    const float* rec_lo = (const float*)d_in[3];
    const float* rec_hi = (const float*)d_in[4];
    const float* sp_c   = (const float*)d_in[5];
    const int*   sp_i   = (const int*)d_in[6];
    float* out = (float*)d_out;

    const int Brows = in_sizes[0] / D_LEN;   // 32768
    wavecore_kernel<<<Brows, 256, 0, stream>>>(x, dec_lo, dec_hi, rec_lo, rec_hi,
                                               sp_c, sp_i, out);
}